// Round 1
// baseline (130.592 us; speedup 1.0000x reference)
//
#include <hip/hip_runtime.h>

#define LSEQ 384
#define DIM 256
#define H 32
#define ODIM 128
#define EPSV 1e-5f

// ---------------------------------------------------------------------------
// Kernel 1: LayerNorm + a = xn @ Wa^T, bT = (xn @ Wb^T)^T
// One block per row i (384 blocks, 256 threads).
// ---------------------------------------------------------------------------
__global__ __launch_bounds__(256) void ln_ab_kernel(
    const float* __restrict__ x, const float* __restrict__ gamma,
    const float* __restrict__ beta, const float* __restrict__ Wa,
    const float* __restrict__ Wb, float* __restrict__ a_g,
    float* __restrict__ bT_g) {
  const int i = blockIdx.x;
  const int tid = threadIdx.x;
  __shared__ float xn_s[DIM];
  __shared__ float psum[256];
  __shared__ float red_s[4];
  __shared__ float mu_s, rs_s;

  float xv = x[i * DIM + tid];

  // block mean
  float s = xv;
#pragma unroll
  for (int off = 32; off > 0; off >>= 1) s += __shfl_down(s, off, 64);
  const int wave = tid >> 6, lane = tid & 63;
  if (lane == 0) red_s[wave] = s;
  __syncthreads();
  if (tid == 0) mu_s = (red_s[0] + red_s[1] + red_s[2] + red_s[3]) * (1.0f / DIM);
  __syncthreads();
  const float mu = mu_s;
  const float dv = xv - mu;

  // block variance
  float s2 = dv * dv;
#pragma unroll
  for (int off = 32; off > 0; off >>= 1) s2 += __shfl_down(s2, off, 64);
  if (lane == 0) red_s[wave] = s2;
  __syncthreads();
  if (tid == 0)
    rs_s = rsqrtf((red_s[0] + red_s[1] + red_s[2] + red_s[3]) * (1.0f / DIM) + EPSV);
  __syncthreads();

  xn_s[tid] = dv * rs_s * gamma[tid] + beta[tid];
  __syncthreads();

  // 64 outputs (32 for a, 32 for b); 4 threads per output split over k.
  const int out = tid >> 2;      // 0..63
  const int part = tid & 3;      // 0..3
  const int which = out >> 5;    // 0 = a, 1 = b
  const int c = out & 31;
  const float* W = which ? Wb : Wa;
  const float4* Wrow = (const float4*)(W + c * DIM);
  const float4* xn4 = (const float4*)xn_s;
  float acc = 0.f;
#pragma unroll
  for (int k = part * 16; k < part * 16 + 16; ++k) {
    float4 w = Wrow[k];
    float4 xx = xn4[k];
    acc += w.x * xx.x + w.y * xx.y + w.z * xx.z + w.w * xx.w;
  }
  psum[tid] = acc;
  __syncthreads();
  if (tid < 64) {
    float v = psum[tid * 4] + psum[tid * 4 + 1] + psum[tid * 4 + 2] + psum[tid * 4 + 3];
    const int wh = tid >> 5, cc = tid & 31;
    if (wh == 0) a_g[i * H + cc] = v;
    else         bT_g[cc * LSEQ + i] = v;
  }
}

// ---------------------------------------------------------------------------
// Kernel 2: t[i, o, d] = sum_c a[i,c] * Wo[o, c*32 + d]
// 2 rows of i per block (192 blocks, 256 threads). Thread handles one o and
// half the d-range (16 d's) for both i's -> 32 accumulators.
// t stored as [i][o][d], d fastest.
// ---------------------------------------------------------------------------
__global__ __launch_bounds__(256) void t_kernel(
    const float* __restrict__ a_g, const float* __restrict__ Wo,
    float* __restrict__ t_g) {
  const int i0 = blockIdx.x * 2;
  const int tid = threadIdx.x;
  const int o = tid >> 1;   // 0..127
  const int dh = tid & 1;   // which 16-d half
  __shared__ float a_s[2][H];
  if (tid < 64) a_s[tid >> 5][tid & 31] = a_g[(i0 + (tid >> 5)) * H + (tid & 31)];
  __syncthreads();

  float4 acc[2][4];
#pragma unroll
  for (int ii = 0; ii < 2; ++ii)
#pragma unroll
    for (int g = 0; g < 4; ++g) acc[ii][g] = make_float4(0.f, 0.f, 0.f, 0.f);

  const float4* W4 = (const float4*)Wo;
#pragma unroll 4
  for (int c = 0; c < H; ++c) {
    const int base = o * 256 + c * 8 + dh * 4;  // float4 index into Wo row
    const float a0 = a_s[0][c];
    const float a1 = a_s[1][c];
#pragma unroll
    for (int g = 0; g < 4; ++g) {
      float4 w = W4[base + g];
      acc[0][g].x += a0 * w.x; acc[0][g].y += a0 * w.y;
      acc[0][g].z += a0 * w.z; acc[0][g].w += a0 * w.w;
      acc[1][g].x += a1 * w.x; acc[1][g].y += a1 * w.y;
      acc[1][g].z += a1 * w.z; acc[1][g].w += a1 * w.w;
    }
  }

  float4* t4 = (float4*)t_g;
#pragma unroll
  for (int ii = 0; ii < 2; ++ii) {
    const int b4 = (i0 + ii) * (ODIM * H / 4) + o * 8 + dh * 4;
#pragma unroll
    for (int g = 0; g < 4; ++g) t4[b4 + g] = acc[ii][g];
  }
}

// ---------------------------------------------------------------------------
// Kernel 3: z[i, j, o] = sum_d t[i,o,d] * b[j,d] + bo[o]
// Block = (i, j-tile of 64). 256 threads = 32 (o, float4) x 8 (j-groups of 8).
// t[i] transposed into LDS tt[d][o] (padded to 132), bT rows in LDS bt[d][j].
// Each thread: 8j x 4o register tile, K=32 fully unrolled.
// ---------------------------------------------------------------------------
#define FMA4(A, S, T)                                        \
  do {                                                       \
    (A).x += (S) * (T).x; (A).y += (S) * (T).y;              \
    (A).z += (S) * (T).z; (A).w += (S) * (T).w;              \
  } while (0)

__global__ __launch_bounds__(256) void z_kernel(
    const float* __restrict__ t_g, const float* __restrict__ bT_g,
    const float* __restrict__ bo, float* __restrict__ z) {
  const int i = blockIdx.x;       // 0..383
  const int jt = blockIdx.y;      // 0..5
  const int tid = threadIdx.x;
  const int ot = tid & 31;        // o-quad index (o = 4*ot .. 4*ot+3)
  const int jg = tid >> 5;        // 0..7 (j-group of 8)

  __shared__ float tt[H][132];    // [d][o], padded: row stride 132 floats
  __shared__ float bt[H][64];     // [d][j within tile]

  // Load t[i] (4096 floats) coalesced, transpose into tt.
  const float4* t4 = (const float4*)(t_g + i * (ODIM * H));
#pragma unroll
  for (int k = 0; k < 4; ++k) {
    const int f = tid + k * 256;
    float4 v = t4[f];
    const int o = f >> 3;
    const int d = (f & 7) * 4;
    tt[d][o] = v.x; tt[d + 1][o] = v.y; tt[d + 2][o] = v.z; tt[d + 3][o] = v.w;
  }
  // Load bT rows for this j-tile (32 x 64 floats).
#pragma unroll
  for (int k = 0; k < 8; ++k) {
    const int idx = tid + k * 256;
    const int d = idx >> 6, col = idx & 63;
    bt[d][col] = bT_g[d * LSEQ + jt * 64 + col];
  }
  __syncthreads();

  const float4 bov = ((const float4*)bo)[ot];
  float4 acc[8];
#pragma unroll
  for (int jj = 0; jj < 8; ++jj) acc[jj] = bov;

#pragma unroll
  for (int d = 0; d < H; ++d) {
    const float4 tv = *(const float4*)&tt[d][ot * 4];
    const float4 b0 = *(const float4*)&bt[d][jg * 8];
    const float4 b1 = *(const float4*)&bt[d][jg * 8 + 4];
    FMA4(acc[0], b0.x, tv); FMA4(acc[1], b0.y, tv);
    FMA4(acc[2], b0.z, tv); FMA4(acc[3], b0.w, tv);
    FMA4(acc[4], b1.x, tv); FMA4(acc[5], b1.y, tv);
    FMA4(acc[6], b1.z, tv); FMA4(acc[7], b1.w, tv);
  }

  float4* z4 = (float4*)z;
  const int jbase = jt * 64 + jg * 8;
#pragma unroll
  for (int jj = 0; jj < 8; ++jj) {
    z4[(size_t)(i * LSEQ + jbase + jj) * 32 + ot] = acc[jj];
  }
}

// ---------------------------------------------------------------------------
extern "C" void kernel_launch(void* const* d_in, const int* in_sizes, int n_in,
                              void* d_out, int out_size, void* d_ws, size_t ws_size,
                              hipStream_t stream) {
  const float* x     = (const float*)d_in[0];
  const float* gamma = (const float*)d_in[1];
  const float* beta  = (const float*)d_in[2];
  const float* Wa    = (const float*)d_in[3];
  const float* Wb    = (const float*)d_in[4];
  const float* Wo    = (const float*)d_in[5];
  const float* bo    = (const float*)d_in[6];
  float* z = (float*)d_out;

  float* ws   = (float*)d_ws;
  float* a_g  = ws;                       // 384*32
  float* bT_g = ws + LSEQ * H;            // 32*384
  float* t_g  = ws + 2 * LSEQ * H;        // 384*128*32 = 1572864 floats

  hipLaunchKernelGGL(ln_ab_kernel, dim3(LSEQ), dim3(256), 0, stream,
                     x, gamma, beta, Wa, Wb, a_g, bT_g);
  hipLaunchKernelGGL(t_kernel, dim3(LSEQ / 2), dim3(256), 0, stream,
                     a_g, Wo, t_g);
  hipLaunchKernelGGL(z_kernel, dim3(LSEQ, LSEQ / 64), dim3(256), 0, stream,
                     t_g, bT_g, bo, z);
}